// Round 1
// baseline (322.602 us; speedup 1.0000x reference)
//
#include <hip/hip_runtime.h>
#include <math.h>

#define N_G   2048
#define W_IMG 128
#define H_IMG 128
#define NPIX  (W_IMG * H_IMG)
#define TANX  0.5f
#define TANY  0.5f
#define ALPHA_MIN (1.0f / 255.0f)
#define T_EPS_C 1e-4f
#define CHUNK 64

struct GParam {               // 48 bytes = 3 x float4
    float px, py, cA, cB;
    float cC, op, pmin, cr;
    float cg, cb, tz, pad;
};

__global__ void gs_preprocess(const float* __restrict__ means3D,
                              const float* __restrict__ opac,
                              const float* __restrict__ colors,
                              const float* __restrict__ scales,
                              const float* __restrict__ rots,
                              const float* __restrict__ viewm,
                              const float* __restrict__ projm,
                              GParam* __restrict__ gp,
                              float* __restrict__ radii_out) {
    int i = blockIdx.x * blockDim.x + threadIdx.x;
    if (i >= N_G) return;

    float mx = means3D[i * 3 + 0], my = means3D[i * 3 + 1], mz = means3D[i * 3 + 2];

    // p_view = [m,1] @ V  (row-vector x row-major 4x4)
    float pv[3];
#pragma unroll
    for (int j = 0; j < 3; j++)
        pv[j] = mx * viewm[0 * 4 + j] + my * viewm[1 * 4 + j] + mz * viewm[2 * 4 + j] + viewm[3 * 4 + j];
    float tz = pv[2];

    float ph[4];
#pragma unroll
    for (int j = 0; j < 4; j++)
        ph[j] = mx * projm[0 * 4 + j] + my * projm[1 * 4 + j] + mz * projm[2 * 4 + j] + projm[3 * 4 + j];
    float inv_w = 1.0f / (ph[3] + 1e-7f);
    float ppx = ph[0] * inv_w, ppy = ph[1] * inv_w;

    // quaternion -> rotation
    float qr = rots[i * 4 + 0], qx = rots[i * 4 + 1], qy = rots[i * 4 + 2], qz = rots[i * 4 + 3];
    float qn = 1.0f / sqrtf(qr * qr + qx * qx + qy * qy + qz * qz);
    qr *= qn; qx *= qn; qy *= qn; qz *= qn;
    float R[3][3] = {
        {1.0f - 2.0f * (qy * qy + qz * qz), 2.0f * (qx * qy - qr * qz), 2.0f * (qx * qz + qr * qy)},
        {2.0f * (qx * qy + qr * qz), 1.0f - 2.0f * (qx * qx + qz * qz), 2.0f * (qy * qz - qr * qx)},
        {2.0f * (qx * qz - qr * qy), 2.0f * (qy * qz + qr * qx), 1.0f - 2.0f * (qx * qx + qy * qy)}};

    float s[3] = {scales[i * 3 + 0], scales[i * 3 + 1], scales[i * 3 + 2]};  // SCALE_MOD = 1
    float M[3][3];
#pragma unroll
    for (int r = 0; r < 3; r++)
#pragma unroll
        for (int cidx = 0; cidx < 3; cidx++) M[r][cidx] = R[r][cidx] * s[cidx];

    // Sigma = M M^T
    float Sg[3][3];
#pragma unroll
    for (int r = 0; r < 3; r++)
#pragma unroll
        for (int k = 0; k < 3; k++)
            Sg[r][k] = M[r][0] * M[k][0] + M[r][1] * M[k][1] + M[r][2] * M[k][2];

    // cov_cam = Vr^T Sigma Vr
    float T1[3][3];
#pragma unroll
    for (int j = 0; j < 3; j++)
#pragma unroll
        for (int l = 0; l < 3; l++)
            T1[j][l] = Sg[j][0] * viewm[0 * 4 + l] + Sg[j][1] * viewm[1 * 4 + l] + Sg[j][2] * viewm[2 * 4 + l];
    float Cc[3][3];
#pragma unroll
    for (int r = 0; r < 3; r++)
#pragma unroll
        for (int l = 0; l < 3; l++)
            Cc[r][l] = viewm[0 * 4 + r] * T1[0][l] + viewm[1 * 4 + r] * T1[1][l] + viewm[2 * 4 + r] * T1[2][l];

    const float fx = W_IMG / (2.0f * TANX), fy = H_IMG / (2.0f * TANY);
    float invtz = 1.0f / tz;
    float txl = fminf(fmaxf(pv[0] * invtz, -1.3f * TANX), 1.3f * TANX) * tz;
    float tyl = fminf(fmaxf(pv[1] * invtz, -1.3f * TANY), 1.3f * TANY) * tz;
    float a0 = fx * invtz, a2 = -fx * txl * invtz * invtz;
    float b1 = fy * invtz, b2 = -fy * tyl * invtz * invtz;

    float c00 = a0 * a0 * Cc[0][0] + 2.0f * a0 * a2 * Cc[0][2] + a2 * a2 * Cc[2][2];
    float c11 = b1 * b1 * Cc[1][1] + 2.0f * b1 * b2 * Cc[1][2] + b2 * b2 * Cc[2][2];
    float c01 = a0 * b1 * Cc[0][1] + a0 * b2 * Cc[0][2] + a2 * b1 * Cc[1][2] + a2 * b2 * Cc[2][2];

    float a = c00 + 0.3f, c = c11 + 0.3f, b = c01;
    float det = a * c - b * b;
    bool valid = (tz > 0.2f) && (det > 0.0f);
    float det_s = (det > 0.0f) ? det : 1.0f;
    float conA = c / det_s, conB = -b / det_s, conC = a / det_s;
    float mid = 0.5f * (a + c);
    float lam = mid + sqrtf(fmaxf(0.1f, mid * mid - det));
    float radf = valid ? ceilf(3.0f * sqrtf(lam)) : 0.0f;
    radii_out[i] = (float)(int)radf;

    float op = opac[i];
    GParam g;
    g.px = ((ppx + 1.0f) * (float)W_IMG - 1.0f) * 0.5f;
    g.py = ((ppy + 1.0f) * (float)H_IMG - 1.0f) * 0.5f;
    g.cA = conA; g.cB = conB; g.cC = conC;
    g.op = op;
    // pre-filter: alpha >= ALPHA_MIN requires power >= log(ALPHA_MIN/op); 1e-3 slack,
    // exact test happens after exp. Invalid gaussians can never pass (power <= 0).
    g.pmin = valid ? (logf(ALPHA_MIN / op) - 1e-3f) : 3.0e38f;
    g.cr = colors[i * 3 + 0]; g.cg = colors[i * 3 + 1]; g.cb = colors[i * 3 + 2];
    g.tz = tz; g.pad = 0.0f;
    gp[i] = g;
}

// stable ascending rank by tz (matches jnp.argsort), scatter AoS into depth order
__global__ void gs_sort(const GParam* __restrict__ gp, GParam* __restrict__ sg) {
    __shared__ float tzl[N_G];
    int tid = threadIdx.x;
    for (int k = tid; k < N_G; k += 256) tzl[k] = gp[k].tz;
    __syncthreads();
    int i = blockIdx.x * 256 + tid;
    float my_tz = tzl[i];
    int rank = 0;
    for (int j = 0; j < N_G; j++) {
        float t = tzl[j];
        rank += (t < my_tz) || (t == my_tz && j < i);
    }
    sg[rank] = gp[i];
}

__global__ __launch_bounds__(CHUNK) void gs_render(const GParam* __restrict__ sg,
                                                   const float* __restrict__ bg,
                                                   float* __restrict__ out) {
    __shared__ GParam lds[CHUNK];
    int tid = threadIdx.x;
    int pid = blockIdx.x * CHUNK + tid;        // pixel id, y*W + x
    float gx = (float)(pid & (W_IMG - 1));
    float gy = (float)(pid >> 7);

    float T = 1.0f, cr = 0.0f, cg = 0.0f, cb = 0.0f, dep = 0.0f;
    int cnt = 0;

    for (int base = 0; base < N_G; base += CHUNK) {
        __syncthreads();
        const float4* src = (const float4*)(sg + base);
        float4* dst = (float4*)lds;
        for (int k = tid; k < CHUNK * 3; k += CHUNK) dst[k] = src[k];
        __syncthreads();

        for (int j = 0; j < CHUNK; j++) {
            GParam g = lds[j];
            float dx = g.px - gx, dy = g.py - gy;
            float power = -0.5f * (g.cA * dx * dx + g.cC * dy * dy) - g.cB * dx * dy;
            if (power <= 0.0f && power >= g.pmin) {
                float alpha = fminf(0.99f, g.op * __expf(power));
                if (alpha >= ALPHA_MIN) {
                    if (T > T_EPS_C) {
                        float w = alpha * T;
                        cr += w * g.cr; cg += w * g.cg; cb += w * g.cb;
                        dep += w * g.tz;
                        cnt++;
                    }
                    T *= (1.0f - alpha);
                }
            }
        }
    }

    cr += T * bg[0]; cg += T * bg[1]; cb += T * bg[2];

    out[0 * NPIX + pid] = cr;
    out[1 * NPIX + pid] = cg;
    out[2 * NPIX + pid] = cb;
    out[3 * NPIX + pid] = dep;                 // depth
    out[4 * NPIX + N_G + pid] = (float)cnt;    // counter (after radii block)
}

extern "C" void kernel_launch(void* const* d_in, const int* in_sizes, int n_in,
                              void* d_out, int out_size, void* d_ws, size_t ws_size,
                              hipStream_t stream) {
    const float* bg      = (const float*)d_in[0];
    const float* means3D = (const float*)d_in[1];
    // d_in[2] = means2D, unused
    const float* opac    = (const float*)d_in[3];
    const float* colors  = (const float*)d_in[4];
    const float* scales  = (const float*)d_in[5];
    const float* rots    = (const float*)d_in[6];
    const float* viewm   = (const float*)d_in[7];
    const float* projm   = (const float*)d_in[8];

    float* out = (float*)d_out;
    GParam* gp = (GParam*)d_ws;                       // unsorted params
    GParam* sg = (GParam*)((char*)d_ws + N_G * sizeof(GParam));  // depth-sorted

    float* radii_out = out + 4 * NPIX;                // after color(3*NPIX)+depth(NPIX)

    gs_preprocess<<<N_G / 256, 256, 0, stream>>>(means3D, opac, colors, scales, rots,
                                                 viewm, projm, gp, radii_out);
    gs_sort<<<N_G / 256, 256, 0, stream>>>(gp, sg);
    gs_render<<<NPIX / CHUNK, CHUNK, 0, stream>>>(sg, bg, out);
}

// Round 2
// 85.108 us; speedup vs baseline: 3.7905x; 3.7905x over previous
//
#include <hip/hip_runtime.h>
#include <math.h>

#define N_G   2048
#define W_IMG 128
#define H_IMG 128
#define NPIX  (W_IMG * H_IMG)
#define TANX  0.5f
#define TANY  0.5f
#define ALPHA_MIN (1.0f / 255.0f)
#define T_EPS_C 1e-4f

// Unsorted, 48B: bbox + params
struct __align__(16) UParam {
    float4 bb;   // px, py, ex, ey   (ex/ey = exact alpha-gate half-extents)
    float4 f1;   // cA, cB, cC, op
    float4 f2;   // cr, cg, cb, tz
};
// Sorted, split SoA: bbox array (coalesced cull scan) + 32B render params
struct __align__(16) SParam {
    float4 f1;   // cA, cB, cC, op
    float4 f2;   // cr, cg, cb, tz
};

__global__ void gs_preprocess(const float* __restrict__ means3D,
                              const float* __restrict__ opac,
                              const float* __restrict__ colors,
                              const float* __restrict__ scales,
                              const float* __restrict__ rots,
                              const float* __restrict__ viewm,
                              const float* __restrict__ projm,
                              UParam* __restrict__ gp,
                              float* __restrict__ radii_out) {
    int i = blockIdx.x * blockDim.x + threadIdx.x;
    if (i >= N_G) return;

    float mx = means3D[i * 3 + 0], my = means3D[i * 3 + 1], mz = means3D[i * 3 + 2];

    float pv[3];
#pragma unroll
    for (int j = 0; j < 3; j++)
        pv[j] = mx * viewm[0 * 4 + j] + my * viewm[1 * 4 + j] + mz * viewm[2 * 4 + j] + viewm[3 * 4 + j];
    float tz = pv[2];

    float ph[4];
#pragma unroll
    for (int j = 0; j < 4; j++)
        ph[j] = mx * projm[0 * 4 + j] + my * projm[1 * 4 + j] + mz * projm[2 * 4 + j] + projm[3 * 4 + j];
    float inv_w = 1.0f / (ph[3] + 1e-7f);
    float ppx = ph[0] * inv_w, ppy = ph[1] * inv_w;

    float qr = rots[i * 4 + 0], qx = rots[i * 4 + 1], qy = rots[i * 4 + 2], qz = rots[i * 4 + 3];
    float qn = 1.0f / sqrtf(qr * qr + qx * qx + qy * qy + qz * qz);
    qr *= qn; qx *= qn; qy *= qn; qz *= qn;
    float R[3][3] = {
        {1.0f - 2.0f * (qy * qy + qz * qz), 2.0f * (qx * qy - qr * qz), 2.0f * (qx * qz + qr * qy)},
        {2.0f * (qx * qy + qr * qz), 1.0f - 2.0f * (qx * qx + qz * qz), 2.0f * (qy * qz - qr * qx)},
        {2.0f * (qx * qz - qr * qy), 2.0f * (qy * qz + qr * qx), 1.0f - 2.0f * (qx * qx + qy * qy)}};

    float s[3] = {scales[i * 3 + 0], scales[i * 3 + 1], scales[i * 3 + 2]};
    float M[3][3];
#pragma unroll
    for (int r = 0; r < 3; r++)
#pragma unroll
        for (int cidx = 0; cidx < 3; cidx++) M[r][cidx] = R[r][cidx] * s[cidx];

    float Sg[3][3];
#pragma unroll
    for (int r = 0; r < 3; r++)
#pragma unroll
        for (int k = 0; k < 3; k++)
            Sg[r][k] = M[r][0] * M[k][0] + M[r][1] * M[k][1] + M[r][2] * M[k][2];

    float T1[3][3];
#pragma unroll
    for (int j = 0; j < 3; j++)
#pragma unroll
        for (int l = 0; l < 3; l++)
            T1[j][l] = Sg[j][0] * viewm[0 * 4 + l] + Sg[j][1] * viewm[1 * 4 + l] + Sg[j][2] * viewm[2 * 4 + l];
    float Cc[3][3];
#pragma unroll
    for (int r = 0; r < 3; r++)
#pragma unroll
        for (int l = 0; l < 3; l++)
            Cc[r][l] = viewm[0 * 4 + r] * T1[0][l] + viewm[1 * 4 + r] * T1[1][l] + viewm[2 * 4 + r] * T1[2][l];

    const float fx = W_IMG / (2.0f * TANX), fy = H_IMG / (2.0f * TANY);
    float invtz = 1.0f / tz;
    float txl = fminf(fmaxf(pv[0] * invtz, -1.3f * TANX), 1.3f * TANX) * tz;
    float tyl = fminf(fmaxf(pv[1] * invtz, -1.3f * TANY), 1.3f * TANY) * tz;
    float a0 = fx * invtz, a2 = -fx * txl * invtz * invtz;
    float b1 = fy * invtz, b2 = -fy * tyl * invtz * invtz;

    float c00 = a0 * a0 * Cc[0][0] + 2.0f * a0 * a2 * Cc[0][2] + a2 * a2 * Cc[2][2];
    float c11 = b1 * b1 * Cc[1][1] + 2.0f * b1 * b2 * Cc[1][2] + b2 * b2 * Cc[2][2];
    float c01 = a0 * b1 * Cc[0][1] + a0 * b2 * Cc[0][2] + a2 * b1 * Cc[1][2] + a2 * b2 * Cc[2][2];

    float a = c00 + 0.3f, c = c11 + 0.3f, b = c01;
    float det = a * c - b * b;
    bool valid = (tz > 0.2f) && (det > 0.0f);
    float det_s = (det > 0.0f) ? det : 1.0f;
    float conA = c / det_s, conB = -b / det_s, conC = a / det_s;
    float mid = 0.5f * (a + c);
    float lam = mid + sqrtf(fmaxf(0.1f, mid * mid - det));
    float radf = valid ? ceilf(3.0f * sqrtf(lam)) : 0.0f;
    radii_out[i] = (float)(int)radf;

    float op = opac[i];
    // Exact contribution bound: alpha = min(0.99, op*exp(power)) >= 1/255 and
    // power = -q/2 with q = conic quadratic form = d^T cov2d^{-1} d.
    // Requires q <= 2L, L = log(255*op). Extents of that ellipse:
    // |dx| <= sqrt(2L*a), |dy| <= sqrt(2L*c)  (a,c = cov2d diagonal).
    float L = logf(255.0f * op);
    float ex, ey;
    if (valid && L > 0.0f) {
        ex = sqrtf(2.0f * L * a) + 1e-2f;
        ey = sqrtf(2.0f * L * c) + 1e-2f;
    } else {
        ex = -1e9f; ey = -1e9f;   // never intersects any tile
    }

    UParam g;
    g.bb = make_float4(((ppx + 1.0f) * (float)W_IMG - 1.0f) * 0.5f,
                       ((ppy + 1.0f) * (float)H_IMG - 1.0f) * 0.5f, ex, ey);
    g.f1 = make_float4(conA, conB, conC, op);
    g.f2 = make_float4(colors[i * 3 + 0], colors[i * 3 + 1], colors[i * 3 + 2], tz);
    gp[i] = g;
}

// stable ascending rank by tz (matches jnp.argsort); scatter into SoA depth order
__global__ void gs_sort(const UParam* __restrict__ gp,
                        float4* __restrict__ sbb, SParam* __restrict__ sgp) {
    __shared__ float tzl[N_G];
    int tid = threadIdx.x;
    for (int k = tid; k < N_G; k += 256) tzl[k] = gp[k].f2.w;
    __syncthreads();
    int i = blockIdx.x * 256 + tid;
    float my_tz = tzl[i];
    const float4* t4 = (const float4*)tzl;
    int rank = 0;
    for (int j4 = 0; j4 < N_G / 4; j4++) {
        float4 t = t4[j4];
        int j = j4 * 4;
        rank += (t.x < my_tz) || (t.x == my_tz && j + 0 < i);
        rank += (t.y < my_tz) || (t.y == my_tz && j + 1 < i);
        rank += (t.z < my_tz) || (t.z == my_tz && j + 2 < i);
        rank += (t.w < my_tz) || (t.w == my_tz && j + 3 < i);
    }
    UParam g = gp[i];
    sbb[rank] = g.bb;
    sgp[rank].f1 = g.f1;
    sgp[rank].f2 = g.f2;
}

// one block (1 wave, 64 threads) per 8x8 tile; 16x16 tiles
__global__ __launch_bounds__(64) void gs_render(const float4* __restrict__ sbb,
                                                const SParam* __restrict__ sgp,
                                                const float* __restrict__ bg,
                                                float* __restrict__ out) {
    __shared__ unsigned short idxl[N_G];
    __shared__ SParam chunk[64];
    int tid = threadIdx.x;
    int tilex = blockIdx.x & 15, tiley = blockIdx.x >> 4;
    float tx0 = (float)(tilex << 3), ty0 = (float)(tiley << 3);
    float tx1 = tx0 + 7.0f, ty1 = ty0 + 7.0f;

    // Phase A: ordered compaction of gaussians whose alpha-ellipse bbox touches tile
    int count = 0;
    for (int base = 0; base < N_G; base += 64) {
        float4 b = sbb[base + tid];
        bool pred = (b.x >= tx0 - b.z) && (b.x <= tx1 + b.z) &&
                    (b.y >= ty0 - b.w) && (b.y <= ty1 + b.w);
        unsigned long long m = __ballot(pred);
        if (pred)
            idxl[count + __popcll(m & ((1ull << tid) - 1ull))] = (unsigned short)(base + tid);
        count += (int)__popcll(m);
    }
    __syncthreads();

    // Phase B: composite the list, staged to LDS 64 entries at a time
    float gx = (float)((tilex << 3) + (tid & 7));
    float gy = (float)((tiley << 3) + (tid >> 3));
    float T = 1.0f, cr = 0.0f, cg = 0.0f, cb = 0.0f, dep = 0.0f;
    int cnt = 0;

    for (int cbase = 0; cbase < count; cbase += 64) {
        int e = cbase + tid;
        if (e < count) {
            int gi = idxl[e];
            const float4* s = (const float4*)&sgp[gi];
            float4 a1 = s[0], a2 = s[1];
            float4* d = (float4*)&chunk[tid];
            d[0] = a1; d[1] = a2;
        }
        __syncthreads();
        int lim = min(64, count - cbase);
        for (int j = 0; j < lim; j++) {
            float4 f1 = chunk[j].f1;   // cA cB cC op
            float4 f2 = chunk[j].f2;   // cr cg cb tz
            float px = ((const float*)&chunk[j])[0]; (void)px; // unused
            // need px,py: recompute from bbox? No — fetch from idx list path:
            // px,py live in sbb; stage them too via shared second buffer below.
            float dx = f1.x, dy = f1.y; (void)dx; (void)dy;
            break; // placeholder (never taken; real loop below)
        }
        // real loop (uses pxy staged alongside)
        __syncthreads();
        (void)lim;
        cbase = cbase; // no-op
        break;
    }

    // NOTE: the above placeholder path is unreachable-by-design only if count==0.
    // Rewritten cleanly below.
    T = 1.0f; cr = 0.0f; cg = 0.0f; cb = 0.0f; dep = 0.0f; cnt = 0;
    __shared__ float2 cpos[64];
    for (int cbase = 0; cbase < count; cbase += 64) {
        __syncthreads();
        int e = cbase + tid;
        if (e < count) {
            int gi = idxl[e];
            const float4* s = (const float4*)&sgp[gi];
            float4 a1 = s[0], a2 = s[1];
            float4* d = (float4*)&chunk[tid];
            d[0] = a1; d[1] = a2;
            float4 b = sbb[gi];
            cpos[tid] = make_float2(b.x, b.y);
        }
        __syncthreads();
        int lim = min(64, count - cbase);
        for (int j = 0; j < lim; j++) {
            float4 f1 = chunk[j].f1;
            float4 f2 = chunk[j].f2;
            float2 p = cpos[j];
            float dx = p.x - gx, dy = p.y - gy;
            float power = -0.5f * (f1.x * dx * dx + f1.z * dy * dy) - f1.y * dx * dy;
            if (power <= 0.0f) {
                float alpha = fminf(0.99f, f1.w * __expf(power));
                if (alpha >= ALPHA_MIN) {
                    if (T > T_EPS_C) {
                        float w = alpha * T;
                        cr += w * f2.x; cg += w * f2.y; cb += w * f2.z;
                        dep += w * f2.w;
                        cnt++;
                    }
                    T *= (1.0f - alpha);
                }
            }
        }
    }

    cr += T * bg[0]; cg += T * bg[1]; cb += T * bg[2];

    int pid = ((tiley << 3) + (tid >> 3)) * W_IMG + (tilex << 3) + (tid & 7);
    out[0 * NPIX + pid] = cr;
    out[1 * NPIX + pid] = cg;
    out[2 * NPIX + pid] = cb;
    out[3 * NPIX + pid] = dep;
    out[4 * NPIX + N_G + pid] = (float)cnt;
}

extern "C" void kernel_launch(void* const* d_in, const int* in_sizes, int n_in,
                              void* d_out, int out_size, void* d_ws, size_t ws_size,
                              hipStream_t stream) {
    const float* bg      = (const float*)d_in[0];
    const float* means3D = (const float*)d_in[1];
    const float* opac    = (const float*)d_in[3];
    const float* colors  = (const float*)d_in[4];
    const float* scales  = (const float*)d_in[5];
    const float* rots    = (const float*)d_in[6];
    const float* viewm   = (const float*)d_in[7];
    const float* projm   = (const float*)d_in[8];

    float* out = (float*)d_out;
    UParam* gp  = (UParam*)d_ws;                                        // 96 KB
    float4* sbb = (float4*)((char*)d_ws + N_G * sizeof(UParam));        // 32 KB
    SParam* sgp = (SParam*)((char*)sbb + N_G * sizeof(float4));         // 64 KB

    float* radii_out = out + 4 * NPIX;

    gs_preprocess<<<N_G / 256, 256, 0, stream>>>(means3D, opac, colors, scales, rots,
                                                 viewm, projm, gp, radii_out);
    gs_sort<<<N_G / 256, 256, 0, stream>>>(gp, sbb, sgp);
    gs_render<<<256, 64, 0, stream>>>(sbb, sgp, bg, out);
}

// Round 3
// 34.580 us; speedup vs baseline: 9.3290x; 2.4612x over previous
//
#include <hip/hip_runtime.h>
#include <math.h>

#define N_G   2048
#define W_IMG 128
#define H_IMG 128
#define NPIX  (W_IMG * H_IMG)
#define TANX  0.5f
#define TANY  0.5f
#define ALPHA_MIN (1.0f / 255.0f)
#define T_EPS_C 1e-4f

// Unsorted, 48B: bbox + params
struct __align__(16) UParam {
    float4 bb;   // px, py, ex, ey   (ex/ey = exact alpha-gate half-extents)
    float4 f1;   // cA, cB, cC, op
    float4 f2;   // cr, cg, cb, tz
};
// Sorted render params, 32B
struct __align__(16) SParam {
    float4 f1;   // cA, cB, cC, op
    float4 f2;   // cr, cg, cb, tz
};

__global__ void gs_preprocess(const float* __restrict__ means3D,
                              const float* __restrict__ opac,
                              const float* __restrict__ colors,
                              const float* __restrict__ scales,
                              const float* __restrict__ rots,
                              const float* __restrict__ viewm,
                              const float* __restrict__ projm,
                              UParam* __restrict__ gp,
                              float* __restrict__ tz_out,
                              float* __restrict__ radii_out) {
    int i = blockIdx.x * blockDim.x + threadIdx.x;
    if (i >= N_G) return;

    float mx = means3D[i * 3 + 0], my = means3D[i * 3 + 1], mz = means3D[i * 3 + 2];

    float pv[3];
#pragma unroll
    for (int j = 0; j < 3; j++)
        pv[j] = mx * viewm[0 * 4 + j] + my * viewm[1 * 4 + j] + mz * viewm[2 * 4 + j] + viewm[3 * 4 + j];
    float tz = pv[2];

    float ph[4];
#pragma unroll
    for (int j = 0; j < 4; j++)
        ph[j] = mx * projm[0 * 4 + j] + my * projm[1 * 4 + j] + mz * projm[2 * 4 + j] + projm[3 * 4 + j];
    float inv_w = 1.0f / (ph[3] + 1e-7f);
    float ppx = ph[0] * inv_w, ppy = ph[1] * inv_w;

    float qr = rots[i * 4 + 0], qx = rots[i * 4 + 1], qy = rots[i * 4 + 2], qz = rots[i * 4 + 3];
    float qn = 1.0f / sqrtf(qr * qr + qx * qx + qy * qy + qz * qz);
    qr *= qn; qx *= qn; qy *= qn; qz *= qn;
    float R[3][3] = {
        {1.0f - 2.0f * (qy * qy + qz * qz), 2.0f * (qx * qy - qr * qz), 2.0f * (qx * qz + qr * qy)},
        {2.0f * (qx * qy + qr * qz), 1.0f - 2.0f * (qx * qx + qz * qz), 2.0f * (qy * qz - qr * qx)},
        {2.0f * (qx * qz - qr * qy), 2.0f * (qy * qz + qr * qx), 1.0f - 2.0f * (qx * qx + qy * qy)}};

    float s[3] = {scales[i * 3 + 0], scales[i * 3 + 1], scales[i * 3 + 2]};
    float M[3][3];
#pragma unroll
    for (int r = 0; r < 3; r++)
#pragma unroll
        for (int cidx = 0; cidx < 3; cidx++) M[r][cidx] = R[r][cidx] * s[cidx];

    float Sg[3][3];
#pragma unroll
    for (int r = 0; r < 3; r++)
#pragma unroll
        for (int k = 0; k < 3; k++)
            Sg[r][k] = M[r][0] * M[k][0] + M[r][1] * M[k][1] + M[r][2] * M[k][2];

    float T1[3][3];
#pragma unroll
    for (int j = 0; j < 3; j++)
#pragma unroll
        for (int l = 0; l < 3; l++)
            T1[j][l] = Sg[j][0] * viewm[0 * 4 + l] + Sg[j][1] * viewm[1 * 4 + l] + Sg[j][2] * viewm[2 * 4 + l];
    float Cc[3][3];
#pragma unroll
    for (int r = 0; r < 3; r++)
#pragma unroll
        for (int l = 0; l < 3; l++)
            Cc[r][l] = viewm[0 * 4 + r] * T1[0][l] + viewm[1 * 4 + r] * T1[1][l] + viewm[2 * 4 + r] * T1[2][l];

    const float fx = W_IMG / (2.0f * TANX), fy = H_IMG / (2.0f * TANY);
    float invtz = 1.0f / tz;
    float txl = fminf(fmaxf(pv[0] * invtz, -1.3f * TANX), 1.3f * TANX) * tz;
    float tyl = fminf(fmaxf(pv[1] * invtz, -1.3f * TANY), 1.3f * TANY) * tz;
    float a0 = fx * invtz, a2 = -fx * txl * invtz * invtz;
    float b1 = fy * invtz, b2 = -fy * tyl * invtz * invtz;

    float c00 = a0 * a0 * Cc[0][0] + 2.0f * a0 * a2 * Cc[0][2] + a2 * a2 * Cc[2][2];
    float c11 = b1 * b1 * Cc[1][1] + 2.0f * b1 * b2 * Cc[1][2] + b2 * b2 * Cc[2][2];
    float c01 = a0 * b1 * Cc[0][1] + a0 * b2 * Cc[0][2] + a2 * b1 * Cc[1][2] + a2 * b2 * Cc[2][2];

    float a = c00 + 0.3f, c = c11 + 0.3f, b = c01;
    float det = a * c - b * b;
    bool valid = (tz > 0.2f) && (det > 0.0f);
    float det_s = (det > 0.0f) ? det : 1.0f;
    float conA = c / det_s, conB = -b / det_s, conC = a / det_s;
    float mid = 0.5f * (a + c);
    float lam = mid + sqrtf(fmaxf(0.1f, mid * mid - det));
    float radf = valid ? ceilf(3.0f * sqrtf(lam)) : 0.0f;
    radii_out[i] = (float)(int)radf;

    float op = opac[i];
    // alpha >= 1/255 requires d^T conic d <= 2L, L = log(255*op);
    // extents of that ellipse: |dx| <= sqrt(2L*a), |dy| <= sqrt(2L*c).
    float L = logf(255.0f * op);
    float ex, ey;
    if (valid && L > 0.0f) {
        ex = sqrtf(2.0f * L * a) + 1e-2f;
        ey = sqrtf(2.0f * L * c) + 1e-2f;
    } else {
        ex = -1e9f; ey = -1e9f;
    }

    UParam g;
    g.bb = make_float4(((ppx + 1.0f) * (float)W_IMG - 1.0f) * 0.5f,
                       ((ppy + 1.0f) * (float)H_IMG - 1.0f) * 0.5f, ex, ey);
    g.f1 = make_float4(conA, conB, conC, op);
    g.f2 = make_float4(colors[i * 3 + 0], colors[i * 3 + 1], colors[i * 3 + 2], tz);
    gp[i] = g;
    tz_out[i] = tz;
}

// one wave per gaussian: rank by ballot+popcount (stable, matches jnp.argsort),
// then scatter the 48B record into depth order. 512 blocks x 256 threads.
__global__ __launch_bounds__(256) void gs_rank_scatter(const UParam* __restrict__ gp,
                                                       const float* __restrict__ tz_arr,
                                                       float4* __restrict__ sbb,
                                                       SParam* __restrict__ sgp) {
    __shared__ float tzl[N_G];
    int tid = threadIdx.x;
#pragma unroll
    for (int k = 0; k < N_G / 256; k++) tzl[k * 256 + tid] = tz_arr[k * 256 + tid];
    __syncthreads();

    int wave = tid >> 6, lane = tid & 63;
    int i = blockIdx.x * 4 + wave;
    float my_tz = tzl[i];
    int rank = 0;
#pragma unroll 4
    for (int c = 0; c < N_G / 64; c++) {
        int j = c * 64 + lane;
        float t = tzl[j];
        bool pred = (t < my_tz) || (t == my_tz && j < i);
        unsigned long long m = __ballot(pred);
        rank += (int)__popcll(m);      // wave-uniform
    }
    if (lane < 3) {
        const float4* s = (const float4*)&gp[i];
        float4 v = s[lane];
        if (lane == 0)      sbb[rank] = v;
        else                ((float4*)&sgp[rank])[lane - 1] = v;
    }
}

// one block (1 wave, 64 threads) per 8x8 tile; 16x16 tiles
__global__ __launch_bounds__(64) void gs_render(const float4* __restrict__ sbb,
                                                const SParam* __restrict__ sgp,
                                                const float* __restrict__ bg,
                                                float* __restrict__ out) {
    __shared__ unsigned short idxl[N_G];
    __shared__ SParam chunk[64];
    __shared__ float2 cpos[64];
    int tid = threadIdx.x;
    int tilex = blockIdx.x & 15, tiley = blockIdx.x >> 4;
    float tx0 = (float)(tilex << 3), ty0 = (float)(tiley << 3);
    float tx1 = tx0 + 7.0f, ty1 = ty0 + 7.0f;

    // Phase A: ordered compaction of gaussians whose alpha-ellipse bbox touches tile
    int count = 0;
    for (int base = 0; base < N_G; base += 64) {
        float4 b = sbb[base + tid];
        bool pred = (b.x >= tx0 - b.z) && (b.x <= tx1 + b.z) &&
                    (b.y >= ty0 - b.w) && (b.y <= ty1 + b.w);
        unsigned long long m = __ballot(pred);
        if (pred)
            idxl[count + __popcll(m & ((1ull << tid) - 1ull))] = (unsigned short)(base + tid);
        count += (int)__popcll(m);
    }

    // Phase B: composite the list, staged to LDS 64 entries at a time
    float gx = (float)((tilex << 3) + (tid & 7));
    float gy = (float)((tiley << 3) + (tid >> 3));
    float T = 1.0f, cr = 0.0f, cg = 0.0f, cb = 0.0f, dep = 0.0f;
    int cnt = 0;

    for (int cbase = 0; cbase < count; cbase += 64) {
        __syncthreads();
        int e = cbase + tid;
        if (e < count) {
            int gi = idxl[e];
            const float4* s = (const float4*)&sgp[gi];
            float4 a1 = s[0], a2 = s[1];
            float4* d = (float4*)&chunk[tid];
            d[0] = a1; d[1] = a2;
            float4 b = sbb[gi];
            cpos[tid] = make_float2(b.x, b.y);
        }
        __syncthreads();
        int lim = min(64, count - cbase);
        for (int j = 0; j < lim; j++) {
            float4 f1 = chunk[j].f1;   // cA cB cC op
            float4 f2 = chunk[j].f2;   // cr cg cb tz
            float2 p = cpos[j];
            float dx = p.x - gx, dy = p.y - gy;
            float power = -0.5f * (f1.x * dx * dx + f1.z * dy * dy) - f1.y * dx * dy;
            if (power <= 0.0f) {
                float alpha = fminf(0.99f, f1.w * __expf(power));
                if (alpha >= ALPHA_MIN) {
                    if (T > T_EPS_C) {
                        float w = alpha * T;
                        cr += w * f2.x; cg += w * f2.y; cb += w * f2.z;
                        dep += w * f2.w;
                        cnt++;
                    }
                    T *= (1.0f - alpha);
                }
            }
        }
    }

    cr += T * bg[0]; cg += T * bg[1]; cb += T * bg[2];

    int pid = ((tiley << 3) + (tid >> 3)) * W_IMG + (tilex << 3) + (tid & 7);
    out[0 * NPIX + pid] = cr;
    out[1 * NPIX + pid] = cg;
    out[2 * NPIX + pid] = cb;
    out[3 * NPIX + pid] = dep;
    out[4 * NPIX + N_G + pid] = (float)cnt;
}

extern "C" void kernel_launch(void* const* d_in, const int* in_sizes, int n_in,
                              void* d_out, int out_size, void* d_ws, size_t ws_size,
                              hipStream_t stream) {
    const float* bg      = (const float*)d_in[0];
    const float* means3D = (const float*)d_in[1];
    const float* opac    = (const float*)d_in[3];
    const float* colors  = (const float*)d_in[4];
    const float* scales  = (const float*)d_in[5];
    const float* rots    = (const float*)d_in[6];
    const float* viewm   = (const float*)d_in[7];
    const float* projm   = (const float*)d_in[8];

    float* out = (float*)d_out;
    UParam* gp   = (UParam*)d_ws;                                        // 96 KB
    float4* sbb  = (float4*)((char*)d_ws + N_G * sizeof(UParam));        // 32 KB
    SParam* sgp  = (SParam*)((char*)sbb + N_G * sizeof(float4));         // 64 KB
    float*  tzar = (float*)((char*)sgp + N_G * sizeof(SParam));          // 8 KB

    float* radii_out = out + 4 * NPIX;

    gs_preprocess<<<N_G / 256, 256, 0, stream>>>(means3D, opac, colors, scales, rots,
                                                 viewm, projm, gp, tzar, radii_out);
    gs_rank_scatter<<<N_G / 4, 256, 0, stream>>>(gp, tzar, sbb, sgp);
    gs_render<<<256, 64, 0, stream>>>(sbb, sgp, bg, out);
}

// Round 4
// 29.943 us; speedup vs baseline: 10.7738x; 1.1549x over previous
//
#include <hip/hip_runtime.h>
#include <math.h>

#define N_G   2048
#define W_IMG 128
#define H_IMG 128
#define NPIX  (W_IMG * H_IMG)
#define TANX  0.5f
#define TANY  0.5f
#define ALPHA_MIN (1.0f / 255.0f)
#define T_EPS_C 1e-4f

// Sorted render params, 32B
struct __align__(16) SParam {
    float4 f1;   // cA, cB, cC, op
    float4 f2;   // cr, cg, cb, tz
};

// Fused preprocess + rank + scatter.
// 256 blocks x 256 threads; block b owns gaussians 8b..8b+7 (2 per wave).
// Phase 1: all threads build the full tz table in LDS (cheap: dot with view col 2).
// Phase 2: per wave, ballot-rank its gaussian (stable, matches jnp.argsort),
//          preprocess it redundantly on all lanes, lane 0 scatters to depth slot.
__global__ __launch_bounds__(256) void gs_pre_rank(const float* __restrict__ means3D,
                                                   const float* __restrict__ opac,
                                                   const float* __restrict__ colors,
                                                   const float* __restrict__ scales,
                                                   const float* __restrict__ rots,
                                                   const float* __restrict__ viewm,
                                                   const float* __restrict__ projm,
                                                   float4* __restrict__ sbb,
                                                   SParam* __restrict__ sgp,
                                                   float* __restrict__ radii_out) {
    __shared__ float tzl[N_G];
    int tid = threadIdx.x;
#pragma unroll
    for (int k = 0; k < N_G / 256; k++) {
        int g = k * 256 + tid;
        float mx = means3D[g * 3 + 0], my = means3D[g * 3 + 1], mz = means3D[g * 3 + 2];
        // identical expression to the reference's p_view[:,2]
        tzl[g] = mx * viewm[0 * 4 + 2] + my * viewm[1 * 4 + 2] + mz * viewm[2 * 4 + 2] + viewm[3 * 4 + 2];
    }
    __syncthreads();

    int wave = tid >> 6, lane = tid & 63;
#pragma unroll
    for (int s = 0; s < 2; s++) {
        int i = blockIdx.x * 8 + wave * 2 + s;
        float tz = tzl[i];

        // rank by ballot (wave-uniform result)
        int rank = 0;
#pragma unroll 8
        for (int c = 0; c < N_G / 64; c++) {
            int j = c * 64 + lane;
            float t = tzl[j];
            bool pred = (t < tz) || (t == tz && j < i);
            rank += (int)__popcll(__ballot(pred));
        }

        // full preprocess of gaussian i (redundant across lanes; uniform loads)
        float mx = means3D[i * 3 + 0], my = means3D[i * 3 + 1], mz = means3D[i * 3 + 2];
        float pv0 = mx * viewm[0] + my * viewm[4] + mz * viewm[8] + viewm[12];
        float pv1 = mx * viewm[1] + my * viewm[5] + mz * viewm[9] + viewm[13];

        float ph[4];
#pragma unroll
        for (int j = 0; j < 4; j++)
            ph[j] = mx * projm[0 * 4 + j] + my * projm[1 * 4 + j] + mz * projm[2 * 4 + j] + projm[3 * 4 + j];
        float inv_w = 1.0f / (ph[3] + 1e-7f);
        float ppx = ph[0] * inv_w, ppy = ph[1] * inv_w;

        float qr = rots[i * 4 + 0], qx = rots[i * 4 + 1], qy = rots[i * 4 + 2], qz = rots[i * 4 + 3];
        float qn = 1.0f / sqrtf(qr * qr + qx * qx + qy * qy + qz * qz);
        qr *= qn; qx *= qn; qy *= qn; qz *= qn;
        float R[3][3] = {
            {1.0f - 2.0f * (qy * qy + qz * qz), 2.0f * (qx * qy - qr * qz), 2.0f * (qx * qz + qr * qy)},
            {2.0f * (qx * qy + qr * qz), 1.0f - 2.0f * (qx * qx + qz * qz), 2.0f * (qy * qz - qr * qx)},
            {2.0f * (qx * qz - qr * qy), 2.0f * (qy * qz + qr * qx), 1.0f - 2.0f * (qx * qx + qy * qy)}};

        float sc[3] = {scales[i * 3 + 0], scales[i * 3 + 1], scales[i * 3 + 2]};
        float M[3][3];
#pragma unroll
        for (int r = 0; r < 3; r++)
#pragma unroll
            for (int cx = 0; cx < 3; cx++) M[r][cx] = R[r][cx] * sc[cx];

        float Sg[3][3];
#pragma unroll
        for (int r = 0; r < 3; r++)
#pragma unroll
            for (int k = 0; k < 3; k++)
                Sg[r][k] = M[r][0] * M[k][0] + M[r][1] * M[k][1] + M[r][2] * M[k][2];

        float T1[3][3];
#pragma unroll
        for (int j = 0; j < 3; j++)
#pragma unroll
            for (int l = 0; l < 3; l++)
                T1[j][l] = Sg[j][0] * viewm[0 * 4 + l] + Sg[j][1] * viewm[1 * 4 + l] + Sg[j][2] * viewm[2 * 4 + l];
        float Cc[3][3];
#pragma unroll
        for (int r = 0; r < 3; r++)
#pragma unroll
            for (int l = 0; l < 3; l++)
                Cc[r][l] = viewm[0 * 4 + r] * T1[0][l] + viewm[1 * 4 + r] * T1[1][l] + viewm[2 * 4 + r] * T1[2][l];

        const float fx = W_IMG / (2.0f * TANX), fy = H_IMG / (2.0f * TANY);
        float invtz = 1.0f / tz;
        float txl = fminf(fmaxf(pv0 * invtz, -1.3f * TANX), 1.3f * TANX) * tz;
        float tyl = fminf(fmaxf(pv1 * invtz, -1.3f * TANY), 1.3f * TANY) * tz;
        float a0 = fx * invtz, a2 = -fx * txl * invtz * invtz;
        float b1 = fy * invtz, b2 = -fy * tyl * invtz * invtz;

        float c00 = a0 * a0 * Cc[0][0] + 2.0f * a0 * a2 * Cc[0][2] + a2 * a2 * Cc[2][2];
        float c11 = b1 * b1 * Cc[1][1] + 2.0f * b1 * b2 * Cc[1][2] + b2 * b2 * Cc[2][2];
        float c01 = a0 * b1 * Cc[0][1] + a0 * b2 * Cc[0][2] + a2 * b1 * Cc[1][2] + a2 * b2 * Cc[2][2];

        float a = c00 + 0.3f, c = c11 + 0.3f, b = c01;
        float det = a * c - b * b;
        bool valid = (tz > 0.2f) && (det > 0.0f);
        float det_s = (det > 0.0f) ? det : 1.0f;
        float conA = c / det_s, conB = -b / det_s, conC = a / det_s;
        float mid = 0.5f * (a + c);
        float lam = mid + sqrtf(fmaxf(0.1f, mid * mid - det));
        float radf = valid ? ceilf(3.0f * sqrtf(lam)) : 0.0f;

        float op = opac[i];
        // alpha >= 1/255 requires d^T conic d <= 2L, L = log(255*op);
        // ellipse extents: |dx| <= sqrt(2L*a), |dy| <= sqrt(2L*c).
        float L = logf(255.0f * op);
        float ex, ey;
        if (valid && L > 0.0f) {
            ex = sqrtf(2.0f * L * a) + 1e-2f;
            ey = sqrtf(2.0f * L * c) + 1e-2f;
        } else {
            ex = -1e9f; ey = -1e9f;
        }

        if (lane == 0) {
            radii_out[i] = (float)(int)radf;
            sbb[rank] = make_float4(((ppx + 1.0f) * (float)W_IMG - 1.0f) * 0.5f,
                                    ((ppy + 1.0f) * (float)H_IMG - 1.0f) * 0.5f, ex, ey);
            sgp[rank].f1 = make_float4(conA, conB, conC, op);
            sgp[rank].f2 = make_float4(colors[i * 3 + 0], colors[i * 3 + 1], colors[i * 3 + 2], tz);
        }
    }
}

// one block (1 wave, 64 threads) per 8x8 tile; 16x16 tiles
__global__ __launch_bounds__(64) void gs_render(const float4* __restrict__ sbb,
                                                const SParam* __restrict__ sgp,
                                                const float* __restrict__ bg,
                                                float* __restrict__ out) {
    __shared__ unsigned short idxl[N_G];
    __shared__ float4 cf1[64];
    __shared__ float4 cf2[64];
    __shared__ float2 cpos[64];
    int tid = threadIdx.x;
    int tilex = blockIdx.x & 15, tiley = blockIdx.x >> 4;
    float tx0 = (float)(tilex << 3), ty0 = (float)(tiley << 3);
    float tx1 = tx0 + 7.0f, ty1 = ty0 + 7.0f;

    // Phase A: ordered compaction (static trip count -> unrolled, loads pipelined)
    int count = 0;
#pragma unroll 8
    for (int base = 0; base < N_G; base += 64) {
        float4 b = sbb[base + tid];
        bool pred = (b.x >= tx0 - b.z) && (b.x <= tx1 + b.z) &&
                    (b.y >= ty0 - b.w) && (b.y <= ty1 + b.w);
        unsigned long long m = __ballot(pred);
        if (pred)
            idxl[count + __popcll(m & ((1ull << tid) - 1ull))] = (unsigned short)(base + tid);
        count += (int)__popcll(m);
    }

    float gx = (float)((tilex << 3) + (tid & 7));
    float gy = (float)((tiley << 3) + (tid >> 3));
    float T = 1.0f, cr = 0.0f, cg = 0.0f, cb = 0.0f, dep = 0.0f;
    int cnt = 0;

    auto proc = [&](float4 f1, float4 f2, float2 p) {
        float dx = p.x - gx, dy = p.y - gy;
        float power = -0.5f * (f1.x * dx * dx + f1.z * dy * dy) - f1.y * dx * dy;
        if (power <= 0.0f) {
            float alpha = fminf(0.99f, f1.w * __expf(power));
            if (alpha >= ALPHA_MIN) {
                if (T > T_EPS_C) {
                    float w = alpha * T;
                    cr += w * f2.x; cg += w * f2.y; cb += w * f2.z;
                    dep += w * f2.w;
                    cnt++;
                }
                T *= (1.0f - alpha);
            }
        }
    };

    for (int cbase = 0; cbase < count; cbase += 64) {
        __syncthreads();
        int e = cbase + tid;
        if (e < count) {
            int gi = idxl[e];
            const float4* s = (const float4*)&sgp[gi];
            cf1[tid] = s[0];
            cf2[tid] = s[1];
            float4 b = sbb[gi];
            cpos[tid] = make_float2(b.x, b.y);
        }
        __syncthreads();
        int lim = min(64, count - cbase);
        int j = 0;
        // 4-wide: batch all LDS reads before the dependent T-chain math
        for (; j + 4 <= lim; j += 4) {
            float4 f1a = cf1[j + 0], f1b = cf1[j + 1], f1c = cf1[j + 2], f1d = cf1[j + 3];
            float4 f2a = cf2[j + 0], f2b = cf2[j + 1], f2c = cf2[j + 2], f2d = cf2[j + 3];
            float2 pa = cpos[j + 0], pb = cpos[j + 1], pc = cpos[j + 2], pd = cpos[j + 3];
            proc(f1a, f2a, pa);
            proc(f1b, f2b, pb);
            proc(f1c, f2c, pc);
            proc(f1d, f2d, pd);
        }
        for (; j < lim; j++) proc(cf1[j], cf2[j], cpos[j]);
    }

    cr += T * bg[0]; cg += T * bg[1]; cb += T * bg[2];

    int pid = ((tiley << 3) + (tid >> 3)) * W_IMG + (tilex << 3) + (tid & 7);
    out[0 * NPIX + pid] = cr;
    out[1 * NPIX + pid] = cg;
    out[2 * NPIX + pid] = cb;
    out[3 * NPIX + pid] = dep;
    out[4 * NPIX + N_G + pid] = (float)cnt;
}

extern "C" void kernel_launch(void* const* d_in, const int* in_sizes, int n_in,
                              void* d_out, int out_size, void* d_ws, size_t ws_size,
                              hipStream_t stream) {
    const float* bg      = (const float*)d_in[0];
    const float* means3D = (const float*)d_in[1];
    const float* opac    = (const float*)d_in[3];
    const float* colors  = (const float*)d_in[4];
    const float* scales  = (const float*)d_in[5];
    const float* rots    = (const float*)d_in[6];
    const float* viewm   = (const float*)d_in[7];
    const float* projm   = (const float*)d_in[8];

    float* out = (float*)d_out;
    float4* sbb = (float4*)d_ws;                                  // 32 KB
    SParam* sgp = (SParam*)((char*)d_ws + N_G * sizeof(float4));  // 64 KB

    float* radii_out = out + 4 * NPIX;

    gs_pre_rank<<<256, 256, 0, stream>>>(means3D, opac, colors, scales, rots,
                                         viewm, projm, sbb, sgp, radii_out);
    gs_render<<<256, 64, 0, stream>>>(sbb, sgp, bg, out);
}

// Round 5
// 25.236 us; speedup vs baseline: 12.7835x; 1.1865x over previous
//
#include <hip/hip_runtime.h>
#include <math.h>

#define N_G   2048
#define W_IMG 128
#define H_IMG 128
#define NPIX  (W_IMG * H_IMG)
#define TANX  0.5f
#define TANY  0.5f
#define ALPHA_MIN (1.0f / 255.0f)
#define T_EPS_C 1e-4f

// One block per 8x8 tile (256 blocks = 256 CUs), 256 threads.
// Phase 1: preprocess ALL 2048 gaussians into LDS (8/thread). 96 KB total.
// Phase 2: wave 0 culls against this tile (ordered ballot compaction).
// Phase 3: locally sort the culled subset by (tz, original index) — equals the
//          global stable argsort order restricted to the subset.
// Phase 4: wave 0 composites 64 px straight from LDS.
__global__ __launch_bounds__(256) void gs_fused(const float* __restrict__ means3D,
                                                const float* __restrict__ opac,
                                                const float* __restrict__ colors,
                                                const float* __restrict__ scales,
                                                const float* __restrict__ rots,
                                                const float* __restrict__ viewm,
                                                const float* __restrict__ projm,
                                                const float* __restrict__ bg,
                                                float* __restrict__ out) {
    __shared__ float4 bbx[N_G];   // px, py, ex, ey
    __shared__ float4 pf1[N_G];   // cA, cB, cC, op
    __shared__ float4 pf2[N_G];   // cr, cg, cb, tz
    __shared__ unsigned short lst[N_G];
    __shared__ unsigned short srt[N_G];
    __shared__ float stz[N_G];
    __shared__ int s_count;

    int tid = threadIdx.x;
    int bid = blockIdx.x;
    float* radii_out = out + 4 * NPIX;

    // ---- Phase 1: preprocess all gaussians (8 per thread, coalesced) ----
    for (int k = 0; k < N_G / 256; k++) {
        int i = k * 256 + tid;

        float mx = means3D[i * 3 + 0], my = means3D[i * 3 + 1], mz = means3D[i * 3 + 2];
        float pv0 = mx * viewm[0] + my * viewm[4] + mz * viewm[8]  + viewm[12];
        float pv1 = mx * viewm[1] + my * viewm[5] + mz * viewm[9]  + viewm[13];
        float tz  = mx * viewm[2] + my * viewm[6] + mz * viewm[10] + viewm[14];

        float ph[4];
#pragma unroll
        for (int j = 0; j < 4; j++)
            ph[j] = mx * projm[0 * 4 + j] + my * projm[1 * 4 + j] + mz * projm[2 * 4 + j] + projm[3 * 4 + j];
        float inv_w = 1.0f / (ph[3] + 1e-7f);
        float ppx = ph[0] * inv_w, ppy = ph[1] * inv_w;

        float qr = rots[i * 4 + 0], qx = rots[i * 4 + 1], qy = rots[i * 4 + 2], qz = rots[i * 4 + 3];
        float qn = 1.0f / sqrtf(qr * qr + qx * qx + qy * qy + qz * qz);
        qr *= qn; qx *= qn; qy *= qn; qz *= qn;
        float R[3][3] = {
            {1.0f - 2.0f * (qy * qy + qz * qz), 2.0f * (qx * qy - qr * qz), 2.0f * (qx * qz + qr * qy)},
            {2.0f * (qx * qy + qr * qz), 1.0f - 2.0f * (qx * qx + qz * qz), 2.0f * (qy * qz - qr * qx)},
            {2.0f * (qx * qz - qr * qy), 2.0f * (qy * qz + qr * qx), 1.0f - 2.0f * (qx * qx + qy * qy)}};

        float sc[3] = {scales[i * 3 + 0], scales[i * 3 + 1], scales[i * 3 + 2]};
        float M[3][3];
#pragma unroll
        for (int r = 0; r < 3; r++)
#pragma unroll
            for (int cx = 0; cx < 3; cx++) M[r][cx] = R[r][cx] * sc[cx];

        float Sg[3][3];
#pragma unroll
        for (int r = 0; r < 3; r++)
#pragma unroll
            for (int kk = 0; kk < 3; kk++)
                Sg[r][kk] = M[r][0] * M[kk][0] + M[r][1] * M[kk][1] + M[r][2] * M[kk][2];

        float T1[3][3];
#pragma unroll
        for (int j = 0; j < 3; j++)
#pragma unroll
            for (int l = 0; l < 3; l++)
                T1[j][l] = Sg[j][0] * viewm[0 * 4 + l] + Sg[j][1] * viewm[1 * 4 + l] + Sg[j][2] * viewm[2 * 4 + l];
        float Cc[3][3];
#pragma unroll
        for (int r = 0; r < 3; r++)
#pragma unroll
            for (int l = 0; l < 3; l++)
                Cc[r][l] = viewm[0 * 4 + r] * T1[0][l] + viewm[1 * 4 + r] * T1[1][l] + viewm[2 * 4 + r] * T1[2][l];

        const float fx = W_IMG / (2.0f * TANX), fy = H_IMG / (2.0f * TANY);
        float invtz = 1.0f / tz;
        float txl = fminf(fmaxf(pv0 * invtz, -1.3f * TANX), 1.3f * TANX) * tz;
        float tyl = fminf(fmaxf(pv1 * invtz, -1.3f * TANY), 1.3f * TANY) * tz;
        float a0 = fx * invtz, a2 = -fx * txl * invtz * invtz;
        float b1 = fy * invtz, b2 = -fy * tyl * invtz * invtz;

        float c00 = a0 * a0 * Cc[0][0] + 2.0f * a0 * a2 * Cc[0][2] + a2 * a2 * Cc[2][2];
        float c11 = b1 * b1 * Cc[1][1] + 2.0f * b1 * b2 * Cc[1][2] + b2 * b2 * Cc[2][2];
        float c01 = a0 * b1 * Cc[0][1] + a0 * b2 * Cc[0][2] + a2 * b1 * Cc[1][2] + a2 * b2 * Cc[2][2];

        float a = c00 + 0.3f, c = c11 + 0.3f, b = c01;
        float det = a * c - b * b;
        bool valid = (tz > 0.2f) && (det > 0.0f);
        float det_s = (det > 0.0f) ? det : 1.0f;
        float conA = c / det_s, conB = -b / det_s, conC = a / det_s;
        float mid = 0.5f * (a + c);
        float lam = mid + sqrtf(fmaxf(0.1f, mid * mid - det));
        float radf = valid ? ceilf(3.0f * sqrtf(lam)) : 0.0f;

        float op = opac[i];
        // alpha >= 1/255 requires d^T conic d <= 2L, L = log(255*op);
        // ellipse extents: |dx| <= sqrt(2L*a), |dy| <= sqrt(2L*c).
        float L = logf(255.0f * op);
        float ex, ey;
        if (valid && L > 0.0f) {
            ex = sqrtf(2.0f * L * a) + 1e-2f;
            ey = sqrtf(2.0f * L * c) + 1e-2f;
        } else {
            ex = -1e9f; ey = -1e9f;
        }

        bbx[i] = make_float4(((ppx + 1.0f) * (float)W_IMG - 1.0f) * 0.5f,
                             ((ppy + 1.0f) * (float)H_IMG - 1.0f) * 0.5f, ex, ey);
        pf1[i] = make_float4(conA, conB, conC, op);
        pf2[i] = make_float4(colors[i * 3 + 0], colors[i * 3 + 1], colors[i * 3 + 2], tz);

        if (bid == 0) radii_out[i] = (float)(int)radf;
    }
    __syncthreads();

    int tilex = bid & 15, tiley = bid >> 4;

    // ---- Phase 2: cull (wave 0, ordered ballot compaction from LDS) ----
    if (tid < 64) {
        float tx0 = (float)(tilex << 3), ty0 = (float)(tiley << 3);
        float tx1 = tx0 + 7.0f, ty1 = ty0 + 7.0f;
        int count = 0;
#pragma unroll 8
        for (int base = 0; base < N_G; base += 64) {
            float4 b = bbx[base + tid];
            bool pred = (b.x >= tx0 - b.z) && (b.x <= tx1 + b.z) &&
                        (b.y >= ty0 - b.w) && (b.y <= ty1 + b.w);
            unsigned long long m = __ballot(pred);
            if (pred)
                lst[count + __popcll(m & ((1ull << tid) - 1ull))] = (unsigned short)(base + tid);
            count += (int)__popcll(m);
        }
        if (tid == 0) s_count = count;
    }
    __syncthreads();
    int c = s_count;

    // ---- Phase 3: local stable sort of the subset by (tz, original idx) ----
    for (int t = tid; t < c; t += 256) stz[t] = pf2[lst[t]].w;
    __syncthreads();
    for (int t = tid; t < c; t += 256) {
        float my = stz[t];
        int rank = 0;
        int j = 0;
        const float4* z4 = (const float4*)stz;
        for (; j + 4 <= c; j += 4) {
            float4 v = z4[j >> 2];
            rank += (v.x < my) || (v.x == my && j + 0 < t);
            rank += (v.y < my) || (v.y == my && j + 1 < t);
            rank += (v.z < my) || (v.z == my && j + 2 < t);
            rank += (v.w < my) || (v.w == my && j + 3 < t);
        }
        for (; j < c; j++) {
            float v = stz[j];
            rank += (v < my) || (v == my && j < t);
        }
        srt[rank] = lst[t];
    }
    __syncthreads();

    // ---- Phase 4: composite (wave 0, one thread per pixel, all from LDS) ----
    if (tid < 64) {
        float gx = (float)((tilex << 3) + (tid & 7));
        float gy = (float)((tiley << 3) + (tid >> 3));
        float T = 1.0f, cr = 0.0f, cg = 0.0f, cb = 0.0f, dep = 0.0f;
        int cnt = 0;

        auto proc = [&](float4 f1, float4 f2, float4 b) {
            float dx = b.x - gx, dy = b.y - gy;
            float power = -0.5f * (f1.x * dx * dx + f1.z * dy * dy) - f1.y * dx * dy;
            if (power <= 0.0f) {
                float alpha = fminf(0.99f, f1.w * __expf(power));
                if (alpha >= ALPHA_MIN) {
                    if (T > T_EPS_C) {
                        float w = alpha * T;
                        cr += w * f2.x; cg += w * f2.y; cb += w * f2.z;
                        dep += w * f2.w;
                        cnt++;
                    }
                    T *= (1.0f - alpha);
                }
            }
        };

        int jj = 0;
        for (; jj + 4 <= c; jj += 4) {
            int g0 = srt[jj], g1 = srt[jj + 1], g2 = srt[jj + 2], g3 = srt[jj + 3];
            float4 f1a = pf1[g0], f1b = pf1[g1], f1c = pf1[g2], f1d = pf1[g3];
            float4 f2a = pf2[g0], f2b = pf2[g1], f2c = pf2[g2], f2d = pf2[g3];
            float4 ba = bbx[g0], bb = bbx[g1], bc = bbx[g2], bd = bbx[g3];
            proc(f1a, f2a, ba);
            proc(f1b, f2b, bb);
            proc(f1c, f2c, bc);
            proc(f1d, f2d, bd);
            if (__all(T <= T_EPS_C)) { jj = c; break; }   // bg term error <= 1e-4
        }
        for (; jj < c; jj++) { int g0 = srt[jj]; proc(pf1[g0], pf2[g0], bbx[g0]); }

        cr += T * bg[0]; cg += T * bg[1]; cb += T * bg[2];

        int pid = ((tiley << 3) + (tid >> 3)) * W_IMG + (tilex << 3) + (tid & 7);
        out[0 * NPIX + pid] = cr;
        out[1 * NPIX + pid] = cg;
        out[2 * NPIX + pid] = cb;
        out[3 * NPIX + pid] = dep;
        out[4 * NPIX + N_G + pid] = (float)cnt;
    }
}

extern "C" void kernel_launch(void* const* d_in, const int* in_sizes, int n_in,
                              void* d_out, int out_size, void* d_ws, size_t ws_size,
                              hipStream_t stream) {
    const float* bg      = (const float*)d_in[0];
    const float* means3D = (const float*)d_in[1];
    const float* opac    = (const float*)d_in[3];
    const float* colors  = (const float*)d_in[4];
    const float* scales  = (const float*)d_in[5];
    const float* rots    = (const float*)d_in[6];
    const float* viewm   = (const float*)d_in[7];
    const float* projm   = (const float*)d_in[8];

    gs_fused<<<256, 256, 0, stream>>>(means3D, opac, colors, scales, rots,
                                      viewm, projm, bg, (float*)d_out);
}

// Round 6
// 24.064 us; speedup vs baseline: 13.4058x; 1.0487x over previous
//
#include <hip/hip_runtime.h>
#include <math.h>

#define N_G   2048
#define W_IMG 128
#define H_IMG 128
#define NPIX  (W_IMG * H_IMG)
#define TANX  0.5f
#define TANY  0.5f
#define ALPHA_MIN (1.0f / 255.0f)
#define T_EPS_C 1e-4f

// One block per 8x8 tile (256 blocks = 256 CUs), 256 threads, ~112 KB LDS.
// Phase 1: preprocess ALL 2048 gaussians into LDS (8/thread), fast-math intrinsics.
// Phase 2: all 4 waves cull against this tile; unordered LDS-atomic compaction
//          (order irrelevant: phase 3 sorts by the unique key (tz, idx)).
// Phase 3: local stable sort of the culled subset == global argsort | subset.
// Phase 4: wave 0 composites 64 px straight from LDS.
__global__ __launch_bounds__(256) void gs_fused(const float* __restrict__ means3D,
                                                const float* __restrict__ opac,
                                                const float* __restrict__ colors,
                                                const float* __restrict__ scales,
                                                const float* __restrict__ rots,
                                                const float* __restrict__ viewm,
                                                const float* __restrict__ projm,
                                                const float* __restrict__ bg,
                                                float* __restrict__ out) {
    __shared__ float4 bbx[N_G];   // px, py, ex, ey
    __shared__ float4 pf1[N_G];   // cA, cB, cC, op
    __shared__ float4 pf2[N_G];   // cr, cg, cb, tz
    __shared__ unsigned short lst[N_G];
    __shared__ unsigned short srt[N_G];
    __shared__ float stz[N_G];
    __shared__ int s_count;

    int tid = threadIdx.x;
    int bid = blockIdx.x;
    float* radii_out = out + 4 * NPIX;
    if (tid == 0) s_count = 0;

    // ---- Phase 1: preprocess all gaussians (8 per thread) ----
    for (int k = 0; k < N_G / 256; k++) {
        int i = k * 256 + tid;

        float mx = means3D[i * 3 + 0], my = means3D[i * 3 + 1], mz = means3D[i * 3 + 2];
        float pv0 = mx * viewm[0] + my * viewm[4] + mz * viewm[8]  + viewm[12];
        float pv1 = mx * viewm[1] + my * viewm[5] + mz * viewm[9]  + viewm[13];
        float tz  = mx * viewm[2] + my * viewm[6] + mz * viewm[10] + viewm[14];

        float ph[4];
#pragma unroll
        for (int j = 0; j < 4; j++)
            ph[j] = mx * projm[0 * 4 + j] + my * projm[1 * 4 + j] + mz * projm[2 * 4 + j] + projm[3 * 4 + j];
        float inv_w = __builtin_amdgcn_rcpf(ph[3] + 1e-7f);
        float ppx = ph[0] * inv_w, ppy = ph[1] * inv_w;

        float qr = rots[i * 4 + 0], qx = rots[i * 4 + 1], qy = rots[i * 4 + 2], qz = rots[i * 4 + 3];
        float qn = __builtin_amdgcn_rsqf(qr * qr + qx * qx + qy * qy + qz * qz);
        qr *= qn; qx *= qn; qy *= qn; qz *= qn;
        float R[3][3] = {
            {1.0f - 2.0f * (qy * qy + qz * qz), 2.0f * (qx * qy - qr * qz), 2.0f * (qx * qz + qr * qy)},
            {2.0f * (qx * qy + qr * qz), 1.0f - 2.0f * (qx * qx + qz * qz), 2.0f * (qy * qz - qr * qx)},
            {2.0f * (qx * qz - qr * qy), 2.0f * (qy * qz + qr * qx), 1.0f - 2.0f * (qx * qx + qy * qy)}};

        float sc[3] = {scales[i * 3 + 0], scales[i * 3 + 1], scales[i * 3 + 2]};
        float M[3][3];
#pragma unroll
        for (int r = 0; r < 3; r++)
#pragma unroll
            for (int cx = 0; cx < 3; cx++) M[r][cx] = R[r][cx] * sc[cx];

        float Sg[3][3];
#pragma unroll
        for (int r = 0; r < 3; r++)
#pragma unroll
            for (int kk = 0; kk < 3; kk++)
                Sg[r][kk] = M[r][0] * M[kk][0] + M[r][1] * M[kk][1] + M[r][2] * M[kk][2];

        float T1[3][3];
#pragma unroll
        for (int j = 0; j < 3; j++)
#pragma unroll
            for (int l = 0; l < 3; l++)
                T1[j][l] = Sg[j][0] * viewm[0 * 4 + l] + Sg[j][1] * viewm[1 * 4 + l] + Sg[j][2] * viewm[2 * 4 + l];
        float Cc[3][3];
#pragma unroll
        for (int r = 0; r < 3; r++)
#pragma unroll
            for (int l = 0; l < 3; l++)
                Cc[r][l] = viewm[0 * 4 + r] * T1[0][l] + viewm[1 * 4 + r] * T1[1][l] + viewm[2 * 4 + r] * T1[2][l];

        const float fx = W_IMG / (2.0f * TANX), fy = H_IMG / (2.0f * TANY);
        float invtz = __builtin_amdgcn_rcpf(tz);
        float txl = fminf(fmaxf(pv0 * invtz, -1.3f * TANX), 1.3f * TANX) * tz;
        float tyl = fminf(fmaxf(pv1 * invtz, -1.3f * TANY), 1.3f * TANY) * tz;
        float a0 = fx * invtz, a2 = -fx * txl * invtz * invtz;
        float b1 = fy * invtz, b2 = -fy * tyl * invtz * invtz;

        float c00 = a0 * a0 * Cc[0][0] + 2.0f * a0 * a2 * Cc[0][2] + a2 * a2 * Cc[2][2];
        float c11 = b1 * b1 * Cc[1][1] + 2.0f * b1 * b2 * Cc[1][2] + b2 * b2 * Cc[2][2];
        float c01 = a0 * b1 * Cc[0][1] + a0 * b2 * Cc[0][2] + a2 * b1 * Cc[1][2] + a2 * b2 * Cc[2][2];

        float a = c00 + 0.3f, c = c11 + 0.3f, b = c01;
        float det = a * c - b * b;
        bool valid = (tz > 0.2f) && (det > 0.0f);
        float det_s = (det > 0.0f) ? det : 1.0f;
        float rdet = __builtin_amdgcn_rcpf(det_s);
        float conA = c * rdet, conB = -b * rdet, conC = a * rdet;
        float mid = 0.5f * (a + c);
        float lam = mid + __builtin_amdgcn_sqrtf(fmaxf(0.1f, mid * mid - det));
        float radf = valid ? ceilf(3.0f * __builtin_amdgcn_sqrtf(lam)) : 0.0f;

        float op = opac[i];
        // alpha >= 1/255 requires d^T conic d <= 2L, L = log(255*op);
        // ellipse extents: |dx| <= sqrt(2L*a), |dy| <= sqrt(2L*c).
        float L = __logf(255.0f * op);
        float ex, ey;
        if (valid && L > 0.0f) {
            ex = __builtin_amdgcn_sqrtf(2.0f * L * a) + 2e-2f;
            ey = __builtin_amdgcn_sqrtf(2.0f * L * c) + 2e-2f;
        } else {
            ex = -1e9f; ey = -1e9f;
        }

        bbx[i] = make_float4(((ppx + 1.0f) * (float)W_IMG - 1.0f) * 0.5f,
                             ((ppy + 1.0f) * (float)H_IMG - 1.0f) * 0.5f, ex, ey);
        pf1[i] = make_float4(conA, conB, conC, op);
        pf2[i] = make_float4(colors[i * 3 + 0], colors[i * 3 + 1], colors[i * 3 + 2], tz);

        if (bid == 0) radii_out[i] = (float)(int)radf;
    }
    __syncthreads();

    int tilex = bid & 15, tiley = bid >> 4;
    int wave = tid >> 6, lane = tid & 63;

    // ---- Phase 2: cull, all 4 waves, unordered LDS-atomic compaction ----
    {
        float tx0 = (float)(tilex << 3), ty0 = (float)(tiley << 3);
        float tx1 = tx0 + 7.0f, ty1 = ty0 + 7.0f;
#pragma unroll
        for (int cc = 0; cc < 8; cc++) {
            int gi = (wave * 8 + cc) * 64 + lane;
            float4 b = bbx[gi];
            bool pred = (b.x >= tx0 - b.z) && (b.x <= tx1 + b.z) &&
                        (b.y >= ty0 - b.w) && (b.y <= ty1 + b.w);
            unsigned long long m = __ballot(pred);
            int n = (int)__popcll(m);
            int base = 0;
            if (lane == 0 && n) base = atomicAdd(&s_count, n);
            base = __shfl(base, 0);
            if (pred)
                lst[base + (int)__popcll(m & ((1ull << lane) - 1ull))] = (unsigned short)gi;
        }
    }
    __syncthreads();
    int c = s_count;

    // ---- Phase 3: local stable sort of subset by unique key (tz, orig idx) ----
    for (int t = tid; t < c; t += 256) stz[t] = pf2[lst[t]].w;
    __syncthreads();
    for (int t = tid; t < c; t += 256) {
        int gi = lst[t];
        float my = stz[t];
        int rank = 0;
        int j = 0;
        const float4* z4 = (const float4*)stz;
        for (; j + 4 <= c; j += 4) {
            float4 v = z4[j >> 2];
            int i0 = lst[j], i1 = lst[j + 1], i2 = lst[j + 2], i3 = lst[j + 3];
            rank += (v.x < my) || (v.x == my && i0 < gi);
            rank += (v.y < my) || (v.y == my && i1 < gi);
            rank += (v.z < my) || (v.z == my && i2 < gi);
            rank += (v.w < my) || (v.w == my && i3 < gi);
        }
        for (; j < c; j++) {
            float v = stz[j];
            rank += (v < my) || (v == my && lst[j] < gi);
        }
        srt[rank] = (unsigned short)gi;
    }
    __syncthreads();

    // ---- Phase 4: composite (wave 0, one thread per pixel, all from LDS) ----
    if (tid < 64) {
        float gx = (float)((tilex << 3) + (tid & 7));
        float gy = (float)((tiley << 3) + (tid >> 3));
        float T = 1.0f, cr = 0.0f, cg = 0.0f, cb = 0.0f, dep = 0.0f;
        int cnt = 0;

        auto proc = [&](float4 f1, float4 f2, float4 b) {
            float dx = b.x - gx, dy = b.y - gy;
            float power = -0.5f * (f1.x * dx * dx + f1.z * dy * dy) - f1.y * dx * dy;
            if (power <= 0.0f) {
                float alpha = fminf(0.99f, f1.w * __expf(power));
                if (alpha >= ALPHA_MIN) {
                    if (T > T_EPS_C) {
                        float w = alpha * T;
                        cr += w * f2.x; cg += w * f2.y; cb += w * f2.z;
                        dep += w * f2.w;
                        cnt++;
                    }
                    T *= (1.0f - alpha);
                }
            }
        };

        int jj = 0;
        for (; jj + 4 <= c; jj += 4) {
            int g0 = srt[jj], g1 = srt[jj + 1], g2 = srt[jj + 2], g3 = srt[jj + 3];
            float4 f1a = pf1[g0], f1b = pf1[g1], f1c = pf1[g2], f1d = pf1[g3];
            float4 f2a = pf2[g0], f2b = pf2[g1], f2c = pf2[g2], f2d = pf2[g3];
            float4 ba = bbx[g0], bb = bbx[g1], bc = bbx[g2], bd = bbx[g3];
            proc(f1a, f2a, ba);
            proc(f1b, f2b, bb);
            proc(f1c, f2c, bc);
            proc(f1d, f2d, bd);
            if (__all(T <= T_EPS_C)) { jj = c; break; }   // bg term error <= 1e-4
        }
        for (; jj < c; jj++) { int g0 = srt[jj]; proc(pf1[g0], pf2[g0], bbx[g0]); }

        cr += T * bg[0]; cg += T * bg[1]; cb += T * bg[2];

        int pid = ((tiley << 3) + (tid >> 3)) * W_IMG + (tilex << 3) + (tid & 7);
        out[0 * NPIX + pid] = cr;
        out[1 * NPIX + pid] = cg;
        out[2 * NPIX + pid] = cb;
        out[3 * NPIX + pid] = dep;
        out[4 * NPIX + N_G + pid] = (float)cnt;
    }
}

extern "C" void kernel_launch(void* const* d_in, const int* in_sizes, int n_in,
                              void* d_out, int out_size, void* d_ws, size_t ws_size,
                              hipStream_t stream) {
    const float* bg      = (const float*)d_in[0];
    const float* means3D = (const float*)d_in[1];
    const float* opac    = (const float*)d_in[3];
    const float* colors  = (const float*)d_in[4];
    const float* scales  = (const float*)d_in[5];
    const float* rots    = (const float*)d_in[6];
    const float* viewm   = (const float*)d_in[7];
    const float* projm   = (const float*)d_in[8];

    gs_fused<<<256, 256, 0, stream>>>(means3D, opac, colors, scales, rots,
                                      viewm, projm, bg, (float*)d_out);
}